// Round 2
// baseline (883.928 us; speedup 1.0000x reference)
//
#include <hip/hip_runtime.h>

// ---------------------------------------------------------------------------
// GCN_35107062677929: 3-layer GCN, N=50000, E=800000, D=128, fp32.
//
// Round 2: (a) hierarchical 3-kernel scan (was 91 us single-block),
//          (b) column-tiled aggregation: 16-col slices (3.2 MB) fit per-XCD
//              L2, grid phases tile-by-tile; final layer's W_out dot is
//              column-separable -> per-tile partial dots atomicAdd'd.
// ---------------------------------------------------------------------------

#define LRELU(v) ((v) > 0.f ? (v) : 0.01f * (v))

__global__ __launch_bounds__(256) void k_count(const int* __restrict__ dst,
                                               int* __restrict__ cnt, int E) {
  int e = blockIdx.x * 256 + threadIdx.x;
  if (e < E) atomicAdd(&cnt[dst[e]], 1);
}

__global__ __launch_bounds__(256) void k_dis(const int* __restrict__ cnt,
                                             float* __restrict__ dis, int N) {
  int i = blockIdx.x * 256 + threadIdx.x;
  if (i < N) dis[i] = rsqrtf((float)cnt[i] + 1.0f);  // +1 self-loop
}

// --- hierarchical exclusive scan: scan1 (per-block) -> scan2 (block sums)
//     -> scan3 (add back). nb = ceil(N/256) must be <= 256.
__global__ __launch_bounds__(256) void k_scan1(const int* __restrict__ cnt,
                                               int* __restrict__ offs,
                                               int* __restrict__ bsum, int N) {
  __shared__ int s[256];
  const int t = threadIdx.x;
  const int i = blockIdx.x * 256 + t;
  const int v = (i < N) ? cnt[i] : 0;
  s[t] = v;
  __syncthreads();
#pragma unroll
  for (int off = 1; off < 256; off <<= 1) {
    int u = (t >= off) ? s[t - off] : 0;
    __syncthreads();
    s[t] += u;
    __syncthreads();
  }
  if (i < N) offs[i] = s[t] - v;  // exclusive
  if (t == 255) bsum[blockIdx.x] = s[255];
}

__global__ __launch_bounds__(256) void k_scan2(int* __restrict__ bsum, int nb) {
  __shared__ int s[256];
  const int t = threadIdx.x;
  const int v = (t < nb) ? bsum[t] : 0;
  s[t] = v;
  __syncthreads();
#pragma unroll
  for (int off = 1; off < 256; off <<= 1) {
    int u = (t >= off) ? s[t - off] : 0;
    __syncthreads();
    s[t] += u;
    __syncthreads();
  }
  if (t < nb) bsum[t] = s[t] - v;  // exclusive
}

__global__ __launch_bounds__(256) void k_scan3(int* __restrict__ offs,
                                               const int* __restrict__ bsum,
                                               int N, int E) {
  const int i = blockIdx.x * 256 + threadIdx.x;
  if (i < N) offs[i] += bsum[blockIdx.x];
  if (i == 0) offs[N] = E;
}

__global__ __launch_bounds__(256) void k_fill(const int* __restrict__ src,
                                              const int* __restrict__ dst,
                                              const int* __restrict__ offs,
                                              int* __restrict__ cur,
                                              int* __restrict__ esrc, int E) {
  int e = blockIdx.x * 256 + threadIdx.x;
  if (e < E) {
    int d = dst[e];
    int pos = offs[d] + atomicAdd(&cur[d], 1);
    esrc[pos] = src[e];
  }
}

// ---------------------------------------------------------------------------
// GEMM: [M,K] @ [K,F] + epilogue. 64-row tile in LDS, 256 threads,
// per-thread micro-tile 8 rows x (F/32) cols.
// EPI 0: out = dis[row] * lrelu(acc + b[col])
// EPI 1: out = lrelu(acc + b[col])
// EPI 2: out = dis[row] * acc
// ---------------------------------------------------------------------------
template <int K, int F, int EPI>
__global__ __launch_bounds__(256) void k_gemm(const float* __restrict__ X,
                                              const float* __restrict__ W,
                                              const float* __restrict__ b,
                                              const float* __restrict__ dis,
                                              float* __restrict__ out, int M) {
  constexpr int TM = 64;
  constexpr int C = F / 32;
  __shared__ float xs[TM * K];
  const int m0 = blockIdx.x * TM;
  const int tid = threadIdx.x;

  {
    const float4* xg = (const float4*)X;
    float4* xs4 = (float4*)xs;
    const int base4 = m0 * (K / 4);
    const int total4 = TM * (K / 4);
    const int limit4 = M * (K / 4);
    for (int idx = tid; idx < total4; idx += 256) {
      float4 v = {0.f, 0.f, 0.f, 0.f};
      if (base4 + idx < limit4) v = xg[base4 + idx];
      xs4[idx] = v;
    }
  }
  __syncthreads();

  const int tc = tid & 31;
  const int tr = tid >> 5;

  float acc[8][C];
#pragma unroll
  for (int j = 0; j < 8; ++j)
#pragma unroll
    for (int c = 0; c < C; ++c) acc[j][c] = 0.f;

  for (int k = 0; k < K; k += 4) {
    float4 xv[8];
#pragma unroll
    for (int j = 0; j < 8; ++j)
      xv[j] = *(const float4*)&xs[(tr * 8 + j) * K + k];
#pragma unroll
    for (int kk = 0; kk < 4; ++kk) {
      float wv[C];
      const float* wrow = &W[(k + kk) * F + tc * C];
      if constexpr (C == 2) {
        float2 t = *(const float2*)wrow;
        wv[0] = t.x; wv[1] = t.y;
      } else if constexpr (C == 4) {
        float4 t = *(const float4*)wrow;
        wv[0] = t.x; wv[1] = t.y; wv[2] = t.z; wv[3] = t.w;
      } else {
        float4 t0 = *(const float4*)wrow;
        float4 t1 = *(const float4*)(wrow + 4);
        wv[0] = t0.x; wv[1] = t0.y; wv[2] = t0.z; wv[3] = t0.w;
        wv[4] = t1.x; wv[5] = t1.y; wv[6] = t1.z; wv[7] = t1.w;
      }
#pragma unroll
      for (int j = 0; j < 8; ++j) {
        const float xval = ((const float*)&xv[j])[kk];
#pragma unroll
        for (int c = 0; c < C; ++c) acc[j][c] += xval * wv[c];
      }
    }
  }

#pragma unroll
  for (int j = 0; j < 8; ++j) {
    const int row = m0 + tr * 8 + j;
    if (row < M) {
      float dv = 1.f;
      if constexpr (EPI != 1) dv = dis[row];
#pragma unroll
      for (int c = 0; c < C; ++c) {
        const int col = tc * C + c;
        float v = acc[j][c];
        if constexpr (EPI == 0) { v += b[col]; v = LRELU(v); v *= dv; }
        if constexpr (EPI == 1) { v += b[col]; v = LRELU(v); }
        if constexpr (EPI == 2) { v *= dv; }
        out[row * F + col] = v;
      }
    }
  }
}

// ---------------------------------------------------------------------------
// Column-tiled aggregation. Grid: (ceil(N/4), F/16). One wave per node per
// 16-col tile; lane = j*16 + c (j = edge subgroup 0..3, c = col 0..15).
// Each iteration gathers 4 edges x 64 B lines; shfl_xor(16,32) folds j.
// MODE 0: out[i*F+col] = dis[i]*acc
// MODE 1: out[i*F+col] = lrelu(dis[i]*acc + b[col])
// MODE 2: partial dot: v = lrelu(dis[i]*acc + b[col]) * Wout[col];
//         16-lane reduce; atomicAdd(out[i], v); (+ bout once on tile 0).
// ---------------------------------------------------------------------------
template <int F, int MODE>
__global__ __launch_bounds__(256) void k_agg_t(const float* __restrict__ G,
                                               const int* __restrict__ esrc,
                                               const int* __restrict__ offs,
                                               const float* __restrict__ dis,
                                               const float* __restrict__ b,
                                               const float* __restrict__ Wout,
                                               const float* __restrict__ bout,
                                               float* __restrict__ out, int N) {
  const int w = threadIdx.x >> 6;           // wave in block (0..3)
  const int i = blockIdx.x * 4 + w;         // node
  if (i >= N) return;
  const int lane = threadIdx.x & 63;
  const int j = lane >> 4;                  // edge subgroup
  const int c = lane & 15;                  // col within tile
  const int c0 = blockIdx.y * 16;
  const int col = c0 + c;

  float acc = (j == 0) ? G[(long)i * F + col] : 0.f;  // self term
  const int e0 = offs[i], e1 = offs[i + 1];
  for (int e = e0 + j; e < e1; e += 4) {
    const int s = esrc[e];
    acc += G[(long)s * F + col];
  }
  // fold the 4 edge subgroups
  acc += __shfl_xor(acc, 16);
  acc += __shfl_xor(acc, 32);

  const float dv = dis[i];
  if constexpr (MODE == 0) {
    if (lane < 16) out[(long)i * F + col] = acc * dv;
  } else if constexpr (MODE == 1) {
    if (lane < 16) {
      float v = acc * dv + b[col];
      out[(long)i * F + col] = LRELU(v);
    }
  } else {  // MODE 2: fused h3 @ W_out
    float v = acc * dv + b[col];
    v = LRELU(v);
    v *= Wout[col];
#pragma unroll
    for (int off = 8; off > 0; off >>= 1) v += __shfl_down(v, off, 16);
    if (lane == 0) {
      if (blockIdx.y == 0) v += bout[0];
      atomicAdd(&out[i], v);
    }
  }
}

// ---------------------------------------------------------------------------

extern "C" void kernel_launch(void* const* d_in, const int* in_sizes, int n_in,
                              void* d_out, int out_size, void* d_ws, size_t ws_size,
                              hipStream_t stream) {
  const float* x     = (const float*)d_in[0];
  const int* eidx    = (const int*)d_in[1];
  const float* W_in  = (const float*)d_in[2];
  const float* b_in  = (const float*)d_in[3];
  const float* W1    = (const float*)d_in[4];
  const float* b1    = (const float*)d_in[5];
  const float* W2    = (const float*)d_in[6];
  const float* b2    = (const float*)d_in[7];
  const float* W3    = (const float*)d_in[8];
  const float* b3    = (const float*)d_in[9];
  const float* W_out = (const float*)d_in[10];
  const float* b_out = (const float*)d_in[11];
  float* out = (float*)d_out;

  const int N = in_sizes[0] / 128;
  const int E = in_sizes[1] / 2;
  const int* src = eidx;
  const int* dst = eidx + E;

  const int nb = (N + 255) / 256;  // scan blocks (<=256 required)

  int* ws_i    = (int*)d_ws;
  int* cnt     = ws_i;                 // N
  int* cur     = ws_i + N;             // N
  int* offs    = ws_i + 2 * N;         // N+1 (padded to N+4)
  int* bsum    = ws_i + 3 * N + 4;     // nb (<=256), pad 256
  int* esrc    = ws_i + 3 * N + 4 + 256;  // E
  float* dis   = (float*)(esrc + E);   // N
  float* buf1  = dis + N;              // N*128
  float* buf2  = buf1 + (size_t)N * 128;  // N*128
  float* buf3  = buf2 + (size_t)N * 128;  // N*256

  hipMemsetAsync(cnt, 0, (size_t)2 * N * sizeof(int), stream);  // cnt + cur
  hipMemsetAsync(out, 0, (size_t)N * sizeof(float), stream);    // final atomics

  const int gE = (E + 255) / 256;
  const int gN = (N + 255) / 256;
  const int gRows = (N + 63) / 64;
  const dim3 gAgg128((N + 3) / 4, 8);
  const dim3 gAgg64((N + 3) / 4, 4);

  // CSR build
  k_count<<<gE, 256, 0, stream>>>(dst, cnt, E);
  k_dis<<<gN, 256, 0, stream>>>(cnt, dis, N);
  k_scan1<<<nb, 256, 0, stream>>>(cnt, offs, bsum, N);
  k_scan2<<<1, 256, 0, stream>>>(bsum, nb);
  k_scan3<<<nb, 256, 0, stream>>>(offs, bsum, N, E);
  k_fill<<<gE, 256, 0, stream>>>(src, dst, offs, cur, esrc, E);

  // g0 = dis .* lrelu(x @ W_in + b_in)
  k_gemm<128, 128, 0><<<gRows, 256, 0, stream>>>(x, W_in, b_in, dis, buf1, N);
  // a0 = A h0
  k_agg_t<128, 0><<<gAgg128, 256, 0, stream>>>(buf1, esrc, offs, dis, nullptr,
                                               nullptr, nullptr, buf2, N);
  // h1 = lrelu(a0 @ W1 + b1)
  k_gemm<128, 256, 1><<<gRows, 256, 0, stream>>>(buf2, W1, b1, nullptr, buf3, N);
  // g2 = dis .* (h1 @ W2)
  k_gemm<256, 128, 2><<<gRows, 256, 0, stream>>>(buf3, W2, nullptr, dis, buf1, N);
  // h2 = lrelu(A-agg(g2) + b2)
  k_agg_t<128, 1><<<gAgg128, 256, 0, stream>>>(buf1, esrc, offs, dis, b2,
                                               nullptr, nullptr, buf2, N);
  // g3 = dis .* (h2 @ W3)
  k_gemm<128, 64, 2><<<gRows, 256, 0, stream>>>(buf2, W3, nullptr, dis, buf3, N);
  // out = (lrelu(A-agg(g3) + b3)) @ W_out + b_out   (fused, per-tile dots)
  k_agg_t<64, 2><<<gAgg64, 256, 0, stream>>>(buf3, esrc, offs, dis, b3,
                                             W_out, b_out, out, N);
}

// Round 3
// 443.703 us; speedup vs baseline: 1.9922x; 1.9922x over previous
//
#include <hip/hip_runtime.h>

// ---------------------------------------------------------------------------
// GCN_35107062677929: 3-layer GCN, N=50000, E=800000, D=128.
//
// Round 3: all intermediate feature buffers in fp16 (halves gather bytes and
// L2 footprint: 25.6 -> 12.8 MB). Aggregation back to full-row-per-wave
// (round-2 column tiling regressed: 64 B tiles < 128 B TCC line => 2x
// overfetch and 6.4 MB line-granular footprint > 4 MiB per-XCD L2).
// Accumulation fp32 everywhere; GEMMs fp32 VALU reading/writing half.
// ---------------------------------------------------------------------------

#define LRELU(v) ((v) > 0.f ? (v) : 0.01f * (v))

typedef __attribute__((ext_vector_type(8))) _Float16 half8;
typedef __attribute__((ext_vector_type(8))) float float8;

__global__ __launch_bounds__(256) void k_count(const int* __restrict__ dst,
                                               int* __restrict__ cnt, int E) {
  int e = blockIdx.x * 256 + threadIdx.x;
  if (e < E) atomicAdd(&cnt[dst[e]], 1);
}

__global__ __launch_bounds__(256) void k_dis(const int* __restrict__ cnt,
                                             float* __restrict__ dis, int N) {
  int i = blockIdx.x * 256 + threadIdx.x;
  if (i < N) dis[i] = rsqrtf((float)cnt[i] + 1.0f);  // +1 self-loop
}

// hierarchical exclusive scan (nb <= 256)
__global__ __launch_bounds__(256) void k_scan1(const int* __restrict__ cnt,
                                               int* __restrict__ offs,
                                               int* __restrict__ bsum, int N) {
  __shared__ int s[256];
  const int t = threadIdx.x;
  const int i = blockIdx.x * 256 + t;
  const int v = (i < N) ? cnt[i] : 0;
  s[t] = v;
  __syncthreads();
#pragma unroll
  for (int off = 1; off < 256; off <<= 1) {
    int u = (t >= off) ? s[t - off] : 0;
    __syncthreads();
    s[t] += u;
    __syncthreads();
  }
  if (i < N) offs[i] = s[t] - v;
  if (t == 255) bsum[blockIdx.x] = s[255];
}

__global__ __launch_bounds__(256) void k_scan2(int* __restrict__ bsum, int nb) {
  __shared__ int s[256];
  const int t = threadIdx.x;
  const int v = (t < nb) ? bsum[t] : 0;
  s[t] = v;
  __syncthreads();
#pragma unroll
  for (int off = 1; off < 256; off <<= 1) {
    int u = (t >= off) ? s[t - off] : 0;
    __syncthreads();
    s[t] += u;
    __syncthreads();
  }
  if (t < nb) bsum[t] = s[t] - v;
}

__global__ __launch_bounds__(256) void k_scan3(int* __restrict__ offs,
                                               const int* __restrict__ bsum,
                                               int N, int E) {
  const int i = blockIdx.x * 256 + threadIdx.x;
  if (i < N) offs[i] += bsum[blockIdx.x];
  if (i == 0) offs[N] = E;
}

__global__ __launch_bounds__(256) void k_fill(const int* __restrict__ src,
                                              const int* __restrict__ dst,
                                              const int* __restrict__ offs,
                                              int* __restrict__ cur,
                                              int* __restrict__ esrc, int E) {
  int e = blockIdx.x * 256 + threadIdx.x;
  if (e < E) {
    int d = dst[e];
    int pos = offs[d] + atomicAdd(&cur[d], 1);
    esrc[pos] = src[e];
  }
}

// ---------------------------------------------------------------------------
// GEMM: [M,K](IT) @ [K,F](f32) -> [M,F](f16), fp32 accumulate.
// 64-row LDS tile (staged as fp32), 256 threads, micro-tile 8 x (F/32).
// EPI 0: dis[row]*lrelu(acc+b)   EPI 1: lrelu(acc+b)   EPI 2: dis[row]*acc
// ---------------------------------------------------------------------------
template <int K, int F, int EPI, typename IT>
__global__ __launch_bounds__(256) void k_gemm(const IT* __restrict__ X,
                                              const float* __restrict__ W,
                                              const float* __restrict__ b,
                                              const float* __restrict__ dis,
                                              _Float16* __restrict__ out, int M) {
  constexpr int TM = 64;
  constexpr int C = F / 32;
  __shared__ float xs[TM * K];
  const int m0 = blockIdx.x * TM;
  const int tid = threadIdx.x;

  if constexpr (sizeof(IT) == 4) {  // fp32 input
    const float4* xg = (const float4*)X;
    float4* xs4 = (float4*)xs;
    const int base4 = m0 * (K / 4);
    const int total4 = TM * (K / 4);
    const int limit4 = M * (K / 4);
    for (int idx = tid; idx < total4; idx += 256) {
      float4 v = {0.f, 0.f, 0.f, 0.f};
      if (base4 + idx < limit4) v = xg[base4 + idx];
      xs4[idx] = v;
    }
  } else {  // fp16 input: 8 elems per 16 B load, convert to fp32 in LDS
    const half8* xg = (const half8*)X;
    const int base8 = m0 * (K / 8);
    const int total8 = TM * (K / 8);
    const int limit8 = M * (K / 8);
    for (int idx = tid; idx < total8; idx += 256) {
      float8 v = {0.f, 0.f, 0.f, 0.f, 0.f, 0.f, 0.f, 0.f};
      if (base8 + idx < limit8) v = __builtin_convertvector(xg[base8 + idx], float8);
      float4* p = (float4*)&xs[idx * 8];
      p[0] = make_float4(v[0], v[1], v[2], v[3]);
      p[1] = make_float4(v[4], v[5], v[6], v[7]);
    }
  }
  __syncthreads();

  const int tc = tid & 31;
  const int tr = tid >> 5;

  float acc[8][C];
#pragma unroll
  for (int j = 0; j < 8; ++j)
#pragma unroll
    for (int c = 0; c < C; ++c) acc[j][c] = 0.f;

  for (int k = 0; k < K; k += 4) {
    float4 xv[8];
#pragma unroll
    for (int j = 0; j < 8; ++j)
      xv[j] = *(const float4*)&xs[(tr * 8 + j) * K + k];
#pragma unroll
    for (int kk = 0; kk < 4; ++kk) {
      float wv[C];
      const float* wrow = &W[(k + kk) * F + tc * C];
      if constexpr (C == 2) {
        float2 t = *(const float2*)wrow;
        wv[0] = t.x; wv[1] = t.y;
      } else if constexpr (C == 4) {
        float4 t = *(const float4*)wrow;
        wv[0] = t.x; wv[1] = t.y; wv[2] = t.z; wv[3] = t.w;
      } else {
        float4 t0 = *(const float4*)wrow;
        float4 t1 = *(const float4*)(wrow + 4);
        wv[0] = t0.x; wv[1] = t0.y; wv[2] = t0.z; wv[3] = t0.w;
        wv[4] = t1.x; wv[5] = t1.y; wv[6] = t1.z; wv[7] = t1.w;
      }
#pragma unroll
      for (int j = 0; j < 8; ++j) {
        const float xval = ((const float*)&xv[j])[kk];
#pragma unroll
        for (int c = 0; c < C; ++c) acc[j][c] += xval * wv[c];
      }
    }
  }

  typedef __attribute__((ext_vector_type(C))) _Float16 halfC;
#pragma unroll
  for (int j = 0; j < 8; ++j) {
    const int row = m0 + tr * 8 + j;
    if (row < M) {
      float dv = 1.f;
      if constexpr (EPI != 1) dv = dis[row];
      halfC hv;
#pragma unroll
      for (int c = 0; c < C; ++c) {
        const int col = tc * C + c;
        float v = acc[j][c];
        if constexpr (EPI == 0) { v += b[col]; v = LRELU(v); v *= dv; }
        if constexpr (EPI == 1) { v += b[col]; v = LRELU(v); }
        if constexpr (EPI == 2) { v *= dv; }
        hv[c] = (_Float16)v;
      }
      *(halfC*)&out[(long)row * F + tc * C] = hv;
    }
  }
}

// ---------------------------------------------------------------------------
// Aggregation, fp16 rows, full row per wave. lane = j*CH + c:
// c = 16 B chunk (8 halfs), j = edge subgroup (JS = 64/CH edges in flight).
// Fold j via shfl_xor. out[i] = dis[i]*(sum_{s->i} G[s] + G[i]).
// MODE 0: write dis*acc (f16)
// MODE 1: write lrelu(dis*acc + b) (f16)
// MODE 2: fused final: out_f32[i] = lrelu(dis*acc + b3) . Wout + bout
// ---------------------------------------------------------------------------
template <int F, int MODE>
__global__ __launch_bounds__(256) void k_agg(const _Float16* __restrict__ G,
                                             const int* __restrict__ esrc,
                                             const int* __restrict__ offs,
                                             const float* __restrict__ dis,
                                             const float* __restrict__ b,
                                             const float* __restrict__ Wout,
                                             const float* __restrict__ bout,
                                             void* __restrict__ out, int N) {
  constexpr int CH = F / 8;    // 16-B chunks per row (16 or 8)
  const int w = threadIdx.x >> 6;
  const int i = blockIdx.x * 4 + w;
  if (i >= N) return;
  const int lane = threadIdx.x & 63;
  const int c = lane & (CH - 1);
  const int j = lane / CH;
  constexpr int JS = 64 / CH;

  float8 acc = {0.f, 0.f, 0.f, 0.f, 0.f, 0.f, 0.f, 0.f};
  if (j == 0)  // self term
    acc = __builtin_convertvector(*(const half8*)&G[(long)i * F + c * 8], float8);
  const int e0 = offs[i], e1 = offs[i + 1];
  for (int e = e0 + j; e < e1; e += JS) {
    const int s = esrc[e];
    acc += __builtin_convertvector(*(const half8*)&G[(long)s * F + c * 8], float8);
  }
  // fold edge subgroups (j bits)
#pragma unroll
  for (int off = CH; off < 64; off <<= 1)
#pragma unroll
    for (int k = 0; k < 8; ++k) acc[k] += __shfl_xor(acc[k], off);

  const float dv = dis[i];
  if constexpr (MODE == 2) {
    float p = 0.f;
#pragma unroll
    for (int k = 0; k < 8; ++k) {
      const int col = c * 8 + k;
      float v = acc[k] * dv + b[col];
      v = LRELU(v);
      p += v * Wout[col];
    }
#pragma unroll
    for (int off = 1; off < CH; off <<= 1) p += __shfl_xor(p, off);
    if (lane == 0) ((float*)out)[i] = p + bout[0];
  } else {
    if (j == 0) {
      half8 hv;
#pragma unroll
      for (int k = 0; k < 8; ++k) {
        float v = acc[k] * dv;
        if constexpr (MODE == 1) { v += b[c * 8 + k]; v = LRELU(v); }
        hv[k] = (_Float16)v;
      }
      *(half8*)&((_Float16*)out)[(long)i * F + c * 8] = hv;
    }
  }
}

// ---------------------------------------------------------------------------

extern "C" void kernel_launch(void* const* d_in, const int* in_sizes, int n_in,
                              void* d_out, int out_size, void* d_ws, size_t ws_size,
                              hipStream_t stream) {
  const float* x     = (const float*)d_in[0];
  const int* eidx    = (const int*)d_in[1];
  const float* W_in  = (const float*)d_in[2];
  const float* b_in  = (const float*)d_in[3];
  const float* W1    = (const float*)d_in[4];
  const float* b1    = (const float*)d_in[5];
  const float* W2    = (const float*)d_in[6];
  const float* b2    = (const float*)d_in[7];
  const float* W3    = (const float*)d_in[8];
  const float* b3    = (const float*)d_in[9];
  const float* W_out = (const float*)d_in[10];
  const float* b_out = (const float*)d_in[11];
  float* out = (float*)d_out;

  const int N = in_sizes[0] / 128;
  const int E = in_sizes[1] / 2;
  const int* src = eidx;
  const int* dst = eidx + E;

  const int nb = (N + 255) / 256;

  int* ws_i    = (int*)d_ws;
  int* cnt     = ws_i;                     // N
  int* cur     = ws_i + N;                 // N
  int* offs    = ws_i + 2 * N;             // N+1 (pad 4)
  int* bsum    = ws_i + 3 * N + 4;         // 256
  int* esrc    = ws_i + 3 * N + 4 + 256;   // E
  float* dis   = (float*)(esrc + E);       // N
  _Float16* buf1 = (_Float16*)(dis + N);          // N*128 f16
  _Float16* buf2 = buf1 + (size_t)N * 128;        // N*128 f16
  _Float16* buf3 = buf2 + (size_t)N * 128;        // N*256 f16

  hipMemsetAsync(cnt, 0, (size_t)2 * N * sizeof(int), stream);  // cnt + cur

  const int gE = (E + 255) / 256;
  const int gN = (N + 255) / 256;
  const int gRows = (N + 63) / 64;
  const int gAgg = (N + 3) / 4;

  // CSR build
  k_count<<<gE, 256, 0, stream>>>(dst, cnt, E);
  k_dis<<<gN, 256, 0, stream>>>(cnt, dis, N);
  k_scan1<<<nb, 256, 0, stream>>>(cnt, offs, bsum, N);
  k_scan2<<<1, 256, 0, stream>>>(bsum, nb);
  k_scan3<<<nb, 256, 0, stream>>>(offs, bsum, N, E);
  k_fill<<<gE, 256, 0, stream>>>(src, dst, offs, cur, esrc, E);

  // g0 = dis .* lrelu(x @ W_in + b_in)            [f32 in, f16 out]
  k_gemm<128, 128, 0, float><<<gRows, 256, 0, stream>>>(x, W_in, b_in, dis, buf1, N);
  // a0 = A h0
  k_agg<128, 0><<<gAgg, 256, 0, stream>>>(buf1, esrc, offs, dis, nullptr,
                                          nullptr, nullptr, buf2, N);
  // h1 = lrelu(a0 @ W1 + b1)
  k_gemm<128, 256, 1, _Float16><<<gRows, 256, 0, stream>>>(buf2, W1, b1, nullptr,
                                                           buf3, N);
  // g2 = dis .* (h1 @ W2)
  k_gemm<256, 128, 2, _Float16><<<gRows, 256, 0, stream>>>(buf3, W2, nullptr, dis,
                                                           buf1, N);
  // h2 = lrelu(A-agg(g2) + b2)
  k_agg<128, 1><<<gAgg, 256, 0, stream>>>(buf1, esrc, offs, dis, b2,
                                          nullptr, nullptr, buf2, N);
  // g3 = dis .* (h2 @ W3)
  k_gemm<128, 64, 2, _Float16><<<gRows, 256, 0, stream>>>(buf2, W3, nullptr, dis,
                                                          buf3, N);
  // out = lrelu(A-agg(g3) + b3) @ W_out + b_out   (fused, no atomics)
  k_agg<64, 2><<<gAgg, 256, 0, stream>>>(buf3, esrc, offs, dis, b3,
                                         W_out, b_out, out, N);
}

// Round 4
// 411.062 us; speedup vs baseline: 2.1504x; 1.0794x over previous
//
#include <hip/hip_runtime.h>

// ---------------------------------------------------------------------------
// GCN_35107062677929: 3-layer GCN, N=50000, E=800000, D=128.
//
// Round 4: GEMMs moved to MFMA f32_16x16x32_f16 (fp16 in, fp32 acc).
//  - A: 64-row fp16 LDS tile, +8-half row pad (round-3 fp32 staging had 64 KB
//    LDS -> 15% occupancy and 400K bank conflicts from 32 B-stride writes).
//  - B: W transposed+fp16 (Wt[F][K]) once per launch; fragments loaded from
//    global (<=64 KB, L1/L2-resident, reused by all blocks).
//  - Fragment maps (HW-verified m89/m91): A/B [free=lane&15][k=quad*8+j],
//    C/D col=lane&15, row=quad*4+reg.
// Aggregation unchanged from round 3 (full fp16 row per wave).
// ---------------------------------------------------------------------------

#define LRELU(v) ((v) > 0.f ? (v) : 0.01f * (v))

typedef __attribute__((ext_vector_type(8))) _Float16 half8;
typedef __attribute__((ext_vector_type(8))) float float8;
typedef __attribute__((ext_vector_type(4))) float floatx4;

__global__ __launch_bounds__(256) void k_count(const int* __restrict__ dst,
                                               int* __restrict__ cnt, int E) {
  int e = blockIdx.x * 256 + threadIdx.x;
  if (e < E) atomicAdd(&cnt[dst[e]], 1);
}

__global__ __launch_bounds__(256) void k_dis(const int* __restrict__ cnt,
                                             float* __restrict__ dis, int N) {
  int i = blockIdx.x * 256 + threadIdx.x;
  if (i < N) dis[i] = rsqrtf((float)cnt[i] + 1.0f);  // +1 self-loop
}

// hierarchical exclusive scan (nb <= 256)
__global__ __launch_bounds__(256) void k_scan1(const int* __restrict__ cnt,
                                               int* __restrict__ offs,
                                               int* __restrict__ bsum, int N) {
  __shared__ int s[256];
  const int t = threadIdx.x;
  const int i = blockIdx.x * 256 + t;
  const int v = (i < N) ? cnt[i] : 0;
  s[t] = v;
  __syncthreads();
#pragma unroll
  for (int off = 1; off < 256; off <<= 1) {
    int u = (t >= off) ? s[t - off] : 0;
    __syncthreads();
    s[t] += u;
    __syncthreads();
  }
  if (i < N) offs[i] = s[t] - v;
  if (t == 255) bsum[blockIdx.x] = s[255];
}

__global__ __launch_bounds__(256) void k_scan2(int* __restrict__ bsum, int nb) {
  __shared__ int s[256];
  const int t = threadIdx.x;
  const int v = (t < nb) ? bsum[t] : 0;
  s[t] = v;
  __syncthreads();
#pragma unroll
  for (int off = 1; off < 256; off <<= 1) {
    int u = (t >= off) ? s[t - off] : 0;
    __syncthreads();
    s[t] += u;
    __syncthreads();
  }
  if (t < nb) bsum[t] = s[t] - v;
}

__global__ __launch_bounds__(256) void k_scan3(int* __restrict__ offs,
                                               const int* __restrict__ bsum,
                                               int N, int E) {
  const int i = blockIdx.x * 256 + threadIdx.x;
  if (i < N) offs[i] += bsum[blockIdx.x];
  if (i == 0) offs[N] = E;
}

__global__ __launch_bounds__(256) void k_fill(const int* __restrict__ src,
                                              const int* __restrict__ dst,
                                              const int* __restrict__ offs,
                                              int* __restrict__ cur,
                                              int* __restrict__ esrc, int E) {
  int e = blockIdx.x * 256 + threadIdx.x;
  if (e < E) {
    int d = dst[e];
    int pos = offs[d] + atomicAdd(&cur[d], 1);
    esrc[pos] = src[e];
  }
}

// W[K,F] f32 -> Wt[F,K] f16. grid: (ceil(F/256), K)
__global__ __launch_bounds__(256) void k_wt(const float* __restrict__ W,
                                            _Float16* __restrict__ Wt,
                                            int K, int F) {
  const int f = blockIdx.x * 256 + threadIdx.x;
  const int k = blockIdx.y;
  if (f < F) Wt[(long)f * K + k] = (_Float16)W[(long)k * F + f];
}

// ---------------------------------------------------------------------------
// MFMA GEMM: [M,K](IT) @ W[K,F] -> [M,F] f16, via Wt[F,K] f16 B-operand.
// 256 thr = 4 waves; wave w computes rows [blk*64 + w*16, +16) x all F cols.
// EPI 0: dis[row]*lrelu(acc+b)   EPI 1: lrelu(acc+b)   EPI 2: dis[row]*acc
// ---------------------------------------------------------------------------
template <int K, int F, int EPI, typename IT>
__global__ __launch_bounds__(256) void k_gemm(const IT* __restrict__ X,
                                              const _Float16* __restrict__ Wt,
                                              const float* __restrict__ b,
                                              const float* __restrict__ dis,
                                              _Float16* __restrict__ out, int M) {
  constexpr int TM = 64;
  constexpr int PAD = 8;           // halves; breaks bank aliasing
  constexpr int LK = K + PAD;
  constexpr int NT = F / 16;       // col tiles
  __shared__ _Float16 xs[TM * LK];

  const int m0 = blockIdx.x * TM;
  const int tid = threadIdx.x;

  // ---- stage A tile (fp16 in LDS), 16 B per lane per iter ----
  constexpr int CPR = K / 8;       // half8 chunks per row
  for (int idx = tid; idx < TM * CPR; idx += 256) {
    const int row = idx / CPR;
    const int kk = idx % CPR;
    const int g = m0 + row;
    half8 h = (half8)(_Float16)0.f;
    if (g < M) {
      if constexpr (sizeof(IT) == 4) {
        const float4* p = (const float4*)&X[(long)g * K + kk * 8];
        float4 a = p[0], c = p[1];
        h[0] = (_Float16)a.x; h[1] = (_Float16)a.y;
        h[2] = (_Float16)a.z; h[3] = (_Float16)a.w;
        h[4] = (_Float16)c.x; h[5] = (_Float16)c.y;
        h[6] = (_Float16)c.z; h[7] = (_Float16)c.w;
      } else {
        h = *(const half8*)&X[(long)g * K + kk * 8];
      }
    }
    *(half8*)&xs[row * LK + kk * 8] = h;
  }
  __syncthreads();

  const int w = tid >> 6;          // wave 0..3
  const int lane = tid & 63;
  const int m = lane & 15;         // free-dim index (A row / B col)
  const int q = lane >> 4;         // quad

  floatx4 acc[NT];
#pragma unroll
  for (int t = 0; t < NT; ++t) acc[t] = (floatx4){0.f, 0.f, 0.f, 0.f};

  const _Float16* arow = &xs[(w * 16 + m) * LK + q * 8];
#pragma unroll
  for (int k0 = 0; k0 < K; k0 += 32) {
    const half8 af = *(const half8*)&arow[k0];
#pragma unroll
    for (int t = 0; t < NT; ++t) {
      const half8 bf = *(const half8*)&Wt[(long)(t * 16 + m) * K + k0 + q * 8];
      acc[t] = __builtin_amdgcn_mfma_f32_16x16x32_f16(af, bf, acc[t], 0, 0, 0);
    }
  }

  // ---- epilogue: C/D row = q*4+r, col = t*16+m ----
  int rows[4];
  float dv4[4];
#pragma unroll
  for (int r = 0; r < 4; ++r) {
    rows[r] = m0 + w * 16 + q * 4 + r;
    dv4[r] = 1.f;
    if constexpr (EPI != 1) {
      if (rows[r] < M) dv4[r] = dis[rows[r]];
    }
  }
#pragma unroll
  for (int t = 0; t < NT; ++t) {
    const int col = t * 16 + m;
    float bc = 0.f;
    if constexpr (EPI != 2) bc = b[col];
#pragma unroll
    for (int r = 0; r < 4; ++r) {
      if (rows[r] < M) {
        float v = acc[t][r];
        if constexpr (EPI == 0) { v += bc; v = LRELU(v); v *= dv4[r]; }
        if constexpr (EPI == 1) { v += bc; v = LRELU(v); }
        if constexpr (EPI == 2) { v *= dv4[r]; }
        out[(long)rows[r] * F + col] = (_Float16)v;
      }
    }
  }
}

// ---------------------------------------------------------------------------
// Aggregation, fp16 rows, full row per wave. lane = j*CH + c.
// MODE 0: dis*acc   MODE 1: lrelu(dis*acc+b)   MODE 2: fused final dot.
// ---------------------------------------------------------------------------
template <int F, int MODE>
__global__ __launch_bounds__(256) void k_agg(const _Float16* __restrict__ G,
                                             const int* __restrict__ esrc,
                                             const int* __restrict__ offs,
                                             const float* __restrict__ dis,
                                             const float* __restrict__ b,
                                             const float* __restrict__ Wout,
                                             const float* __restrict__ bout,
                                             void* __restrict__ out, int N) {
  constexpr int CH = F / 8;
  const int w = threadIdx.x >> 6;
  const int i = blockIdx.x * 4 + w;
  if (i >= N) return;
  const int lane = threadIdx.x & 63;
  const int c = lane & (CH - 1);
  const int j = lane / CH;
  constexpr int JS = 64 / CH;

  float8 acc = {0.f, 0.f, 0.f, 0.f, 0.f, 0.f, 0.f, 0.f};
  if (j == 0)
    acc = __builtin_convertvector(*(const half8*)&G[(long)i * F + c * 8], float8);
  const int e0 = offs[i], e1 = offs[i + 1];
  for (int e = e0 + j; e < e1; e += JS) {
    const int s = esrc[e];
    acc += __builtin_convertvector(*(const half8*)&G[(long)s * F + c * 8], float8);
  }
#pragma unroll
  for (int off = CH; off < 64; off <<= 1)
#pragma unroll
    for (int k = 0; k < 8; ++k) acc[k] += __shfl_xor(acc[k], off);

  const float dv = dis[i];
  if constexpr (MODE == 2) {
    float p = 0.f;
#pragma unroll
    for (int k = 0; k < 8; ++k) {
      const int col = c * 8 + k;
      float v = acc[k] * dv + b[col];
      v = LRELU(v);
      p += v * Wout[col];
    }
#pragma unroll
    for (int off = 1; off < CH; off <<= 1) p += __shfl_xor(p, off);
    if (lane == 0) ((float*)out)[i] = p + bout[0];
  } else {
    if (j == 0) {
      half8 hv;
#pragma unroll
      for (int k = 0; k < 8; ++k) {
        float v = acc[k] * dv;
        if constexpr (MODE == 1) { v += b[c * 8 + k]; v = LRELU(v); }
        hv[k] = (_Float16)v;
      }
      *(half8*)&((_Float16*)out)[(long)i * F + c * 8] = hv;
    }
  }
}

// ---------------------------------------------------------------------------

extern "C" void kernel_launch(void* const* d_in, const int* in_sizes, int n_in,
                              void* d_out, int out_size, void* d_ws, size_t ws_size,
                              hipStream_t stream) {
  const float* x     = (const float*)d_in[0];
  const int* eidx    = (const int*)d_in[1];
  const float* W_in  = (const float*)d_in[2];
  const float* b_in  = (const float*)d_in[3];
  const float* W1    = (const float*)d_in[4];
  const float* b1    = (const float*)d_in[5];
  const float* W2    = (const float*)d_in[6];
  const float* b2    = (const float*)d_in[7];
  const float* W3    = (const float*)d_in[8];
  const float* b3    = (const float*)d_in[9];
  const float* W_out = (const float*)d_in[10];
  const float* b_out = (const float*)d_in[11];
  float* out = (float*)d_out;

  const int N = in_sizes[0] / 128;
  const int E = in_sizes[1] / 2;
  const int* src = eidx;
  const int* dst = eidx + E;
  const int nb = (N + 255) / 256;

  // bump allocator on d_ws, 256 B aligned
  size_t off = 0;
  char* base = (char*)d_ws;
  auto alloc = [&](size_t bytes) -> void* {
    void* p = base + off;
    off = (off + bytes + 255) & ~(size_t)255;
    return p;
  };
  int* cnt        = (int*)alloc((size_t)2 * N * sizeof(int));  // cnt + cur
  int* cur        = cnt + N;
  int* offs       = (int*)alloc((size_t)(N + 4) * sizeof(int));
  int* bsum       = (int*)alloc(256 * sizeof(int));
  int* esrc       = (int*)alloc((size_t)E * sizeof(int));
  float* dis      = (float*)alloc((size_t)N * sizeof(float));
  _Float16* wt_in = (_Float16*)alloc((size_t)128 * 128 * 2);
  _Float16* wt1   = (_Float16*)alloc((size_t)256 * 128 * 2);  // Wt1[256,128]
  _Float16* wt2   = (_Float16*)alloc((size_t)128 * 256 * 2);  // Wt2[128,256]
  _Float16* wt3   = (_Float16*)alloc((size_t)64 * 128 * 2);   // Wt3[64,128]
  _Float16* buf1  = (_Float16*)alloc((size_t)N * 128 * 2);
  _Float16* buf2  = (_Float16*)alloc((size_t)N * 128 * 2);
  _Float16* buf3  = (_Float16*)alloc((size_t)N * 256 * 2);

  hipMemsetAsync(cnt, 0, (size_t)2 * N * sizeof(int), stream);

  const int gE = (E + 255) / 256;
  const int gN = (N + 255) / 256;
  const int gRows = (N + 63) / 64;
  const int gAgg = (N + 3) / 4;

  // weight transpose+convert (independent of CSR)
  k_wt<<<dim3(1, 128), 256, 0, stream>>>(W_in, wt_in, 128, 128);
  k_wt<<<dim3(1, 128), 256, 0, stream>>>(W1, wt1, 128, 256);
  k_wt<<<dim3(1, 256), 256, 0, stream>>>(W2, wt2, 256, 128);
  k_wt<<<dim3(1, 128), 256, 0, stream>>>(W3, wt3, 128, 64);

  // CSR build
  k_count<<<gE, 256, 0, stream>>>(dst, cnt, E);
  k_dis<<<gN, 256, 0, stream>>>(cnt, dis, N);
  k_scan1<<<nb, 256, 0, stream>>>(cnt, offs, bsum, N);
  k_scan2<<<1, 256, 0, stream>>>(bsum, nb);
  k_scan3<<<nb, 256, 0, stream>>>(offs, bsum, N, E);
  k_fill<<<gE, 256, 0, stream>>>(src, dst, offs, cur, esrc, E);

  // g0 = dis .* lrelu(x @ W_in + b_in)
  k_gemm<128, 128, 0, float><<<gRows, 256, 0, stream>>>(x, wt_in, b_in, dis,
                                                        buf1, N);
  // a0 = A h0
  k_agg<128, 0><<<gAgg, 256, 0, stream>>>(buf1, esrc, offs, dis, nullptr,
                                          nullptr, nullptr, buf2, N);
  // h1 = lrelu(a0 @ W1 + b1)
  k_gemm<128, 256, 1, _Float16><<<gRows, 256, 0, stream>>>(buf2, wt1, b1,
                                                           nullptr, buf3, N);
  // g2 = dis .* (h1 @ W2)
  k_gemm<256, 128, 2, _Float16><<<gRows, 256, 0, stream>>>(buf3, wt2, nullptr,
                                                           dis, buf1, N);
  // h2 = lrelu(A-agg(g2) + b2)
  k_agg<128, 1><<<gAgg, 256, 0, stream>>>(buf1, esrc, offs, dis, b2,
                                          nullptr, nullptr, buf2, N);
  // g3 = dis .* (h2 @ W3)
  k_gemm<128, 64, 2, _Float16><<<gRows, 256, 0, stream>>>(buf2, wt3, nullptr,
                                                          dis, buf3, N);
  // out = lrelu(A-agg(g3) + b3) @ W_out + b_out
  k_agg<64, 2><<<gAgg, 256, 0, stream>>>(buf3, esrc, offs, dis, b3,
                                         W_out, b_out, out, N);
}

// Round 5
// 345.226 us; speedup vs baseline: 2.5604x; 1.1907x over previous
//
#include <hip/hip_runtime.h>

// ---------------------------------------------------------------------------
// GCN_35107062677929: 3-layer GCN, N=50000, E=800000, D=128.
//
// Round 5: GEMM K-loop restructured to LDS+registers only.
//   Round-4 failure: B-fragments were global loads inside the K-loop ->
//   ~200cyc L2-hit stalls per MFMA chain, all pipes <7% busy, 59us.
//   Fix: waves split the F dimension (wave w owns F/4 cols for all 64 block
//   rows); that wave's whole B slice fits in <=64 VGPRs/lane, preloaded once
//   before the K-loop. K-loop = 4 ds_read_b128 + 4*NT MFMA per k-chunk.
// Aggregation unchanged from round 3/4 (full fp16 row per wave).
// ---------------------------------------------------------------------------

#define LRELU(v) ((v) > 0.f ? (v) : 0.01f * (v))

typedef __attribute__((ext_vector_type(8))) _Float16 half8;
typedef __attribute__((ext_vector_type(8))) float float8;
typedef __attribute__((ext_vector_type(4))) float floatx4;

__global__ __launch_bounds__(256) void k_count(const int* __restrict__ dst,
                                               int* __restrict__ cnt, int E) {
  int e = blockIdx.x * 256 + threadIdx.x;
  if (e < E) atomicAdd(&cnt[dst[e]], 1);
}

__global__ __launch_bounds__(256) void k_dis(const int* __restrict__ cnt,
                                             float* __restrict__ dis, int N) {
  int i = blockIdx.x * 256 + threadIdx.x;
  if (i < N) dis[i] = rsqrtf((float)cnt[i] + 1.0f);  // +1 self-loop
}

// hierarchical exclusive scan (nb <= 256)
__global__ __launch_bounds__(256) void k_scan1(const int* __restrict__ cnt,
                                               int* __restrict__ offs,
                                               int* __restrict__ bsum, int N) {
  __shared__ int s[256];
  const int t = threadIdx.x;
  const int i = blockIdx.x * 256 + t;
  const int v = (i < N) ? cnt[i] : 0;
  s[t] = v;
  __syncthreads();
#pragma unroll
  for (int off = 1; off < 256; off <<= 1) {
    int u = (t >= off) ? s[t - off] : 0;
    __syncthreads();
    s[t] += u;
    __syncthreads();
  }
  if (i < N) offs[i] = s[t] - v;
  if (t == 255) bsum[blockIdx.x] = s[255];
}

__global__ __launch_bounds__(256) void k_scan2(int* __restrict__ bsum, int nb) {
  __shared__ int s[256];
  const int t = threadIdx.x;
  const int v = (t < nb) ? bsum[t] : 0;
  s[t] = v;
  __syncthreads();
#pragma unroll
  for (int off = 1; off < 256; off <<= 1) {
    int u = (t >= off) ? s[t - off] : 0;
    __syncthreads();
    s[t] += u;
    __syncthreads();
  }
  if (t < nb) bsum[t] = s[t] - v;
}

__global__ __launch_bounds__(256) void k_scan3(int* __restrict__ offs,
                                               const int* __restrict__ bsum,
                                               int N, int E) {
  const int i = blockIdx.x * 256 + threadIdx.x;
  if (i < N) offs[i] += bsum[blockIdx.x];
  if (i == 0) offs[N] = E;
}

__global__ __launch_bounds__(256) void k_fill(const int* __restrict__ src,
                                              const int* __restrict__ dst,
                                              const int* __restrict__ offs,
                                              int* __restrict__ cur,
                                              int* __restrict__ esrc, int E) {
  int e = blockIdx.x * 256 + threadIdx.x;
  if (e < E) {
    int d = dst[e];
    int pos = offs[d] + atomicAdd(&cur[d], 1);
    esrc[pos] = src[e];
  }
}

// W[K,F] f32 -> Wt[F,K] f16. grid: (ceil(F/256), K)
__global__ __launch_bounds__(256) void k_wt(const float* __restrict__ W,
                                            _Float16* __restrict__ Wt,
                                            int K, int F) {
  const int f = blockIdx.x * 256 + threadIdx.x;
  const int k = blockIdx.y;
  if (f < F) Wt[(long)f * K + k] = (_Float16)W[(long)k * F + f];
}

// ---------------------------------------------------------------------------
// MFMA GEMM: [M,K](IT) @ W[K,F] -> [M,F] f16, Wt[F,K] f16 B-operand.
// 256 thr = 4 waves. Block covers 64 rows x F cols; wave w covers cols
// [w*F/4, (w+1)*F/4) for ALL 64 rows. B slice preloaded to VGPRs once.
// Fragment maps (HW-verified m89/m91): A/B [free=lane&15][k=quad*8+j],
// C/D col=lane&15, row=quad*4+reg.
// EPI 0: dis[row]*lrelu(acc+b)   EPI 1: lrelu(acc+b)   EPI 2: dis[row]*acc
// ---------------------------------------------------------------------------
template <int K, int F, int EPI, typename IT>
__global__ __launch_bounds__(256) void k_gemm(const IT* __restrict__ X,
                                              const _Float16* __restrict__ Wt,
                                              const float* __restrict__ b,
                                              const float* __restrict__ dis,
                                              _Float16* __restrict__ out, int M) {
  constexpr int TM = 64;
  constexpr int PAD = 8;           // halves; breaks bank aliasing
  constexpr int LK = K + PAD;
  constexpr int CW = F / 4;        // cols per wave
  constexpr int NT = CW / 16;      // col tiles per wave
  constexpr int NK = K / 32;       // k chunks
  __shared__ _Float16 xs[TM * LK];

  const int m0 = blockIdx.x * TM;
  const int tid = threadIdx.x;
  const int w = tid >> 6;          // wave 0..3
  const int lane = tid & 63;
  const int m = lane & 15;         // free-dim index (A row / B col in tile)
  const int q = lane >> 4;         // quad -> k offset q*8

  // ---- preload this wave's whole B slice into registers (once) ----
  half8 breg[NT][NK];
#pragma unroll
  for (int t = 0; t < NT; ++t)
#pragma unroll
    for (int kc = 0; kc < NK; ++kc)
      breg[t][kc] =
          *(const half8*)&Wt[(long)(w * CW + t * 16 + m) * K + kc * 32 + q * 8];

  // ---- stage A tile (fp16 in LDS), 16 B per lane per iter ----
  constexpr int CPR = K / 8;       // half8 chunks per row
  for (int idx = tid; idx < TM * CPR; idx += 256) {
    const int row = idx / CPR;
    const int kk = idx % CPR;
    const int g = m0 + row;
    half8 h = (half8)(_Float16)0.f;
    if (g < M) {
      if constexpr (sizeof(IT) == 4) {
        const float4* p = (const float4*)&X[(long)g * K + kk * 8];
        float4 a = p[0], c = p[1];
        h[0] = (_Float16)a.x; h[1] = (_Float16)a.y;
        h[2] = (_Float16)a.z; h[3] = (_Float16)a.w;
        h[4] = (_Float16)c.x; h[5] = (_Float16)c.y;
        h[6] = (_Float16)c.z; h[7] = (_Float16)c.w;
      } else {
        h = *(const half8*)&X[(long)g * K + kk * 8];
      }
    }
    *(half8*)&xs[row * LK + kk * 8] = h;
  }
  __syncthreads();

  // ---- K-loop: LDS + MFMA only ----
  floatx4 acc[4][NT];
#pragma unroll
  for (int rt = 0; rt < 4; ++rt)
#pragma unroll
    for (int t = 0; t < NT; ++t) acc[rt][t] = (floatx4){0.f, 0.f, 0.f, 0.f};

#pragma unroll
  for (int kc = 0; kc < NK; ++kc) {
    half8 af[4];
#pragma unroll
    for (int rt = 0; rt < 4; ++rt)
      af[rt] = *(const half8*)&xs[(rt * 16 + m) * LK + kc * 32 + q * 8];
#pragma unroll
    for (int rt = 0; rt < 4; ++rt)
#pragma unroll
      for (int t = 0; t < NT; ++t)
        acc[rt][t] =
            __builtin_amdgcn_mfma_f32_16x16x32_f16(af[rt], breg[t][kc],
                                                   acc[rt][t], 0, 0, 0);
  }

  // ---- epilogue: C/D row = rt*16 + q*4 + r, col = w*CW + t*16 + m ----
#pragma unroll
  for (int rt = 0; rt < 4; ++rt) {
#pragma unroll
    for (int r = 0; r < 4; ++r) {
      const int row = m0 + rt * 16 + q * 4 + r;
      if (row < M) {
        float dv = 1.f;
        if constexpr (EPI != 1) dv = dis[row];
#pragma unroll
        for (int t = 0; t < NT; ++t) {
          const int col = w * CW + t * 16 + m;
          float v = acc[rt][t][r];
          if constexpr (EPI == 0) { v += b[col]; v = LRELU(v); v *= dv; }
          if constexpr (EPI == 1) { v += b[col]; v = LRELU(v); }
          if constexpr (EPI == 2) { v *= dv; }
          out[(long)row * F + col] = (_Float16)v;
        }
      }
    }
  }
}

// ---------------------------------------------------------------------------
// Aggregation, fp16 rows, full row per wave. lane = j*CH + c.
// MODE 0: dis*acc   MODE 1: lrelu(dis*acc+b)   MODE 2: fused final dot.
// ---------------------------------------------------------------------------
template <int F, int MODE>
__global__ __launch_bounds__(256) void k_agg(const _Float16* __restrict__ G,
                                             const int* __restrict__ esrc,
                                             const int* __restrict__ offs,
                                             const float* __restrict__ dis,
                                             const float* __restrict__ b,
                                             const float* __restrict__ Wout,
                                             const float* __restrict__ bout,
                                             void* __restrict__ out, int N) {
  constexpr int CH = F / 8;
  const int w = threadIdx.x >> 6;
  const int i = blockIdx.x * 4 + w;
  if (i >= N) return;
  const int lane = threadIdx.x & 63;
  const int c = lane & (CH - 1);
  const int j = lane / CH;
  constexpr int JS = 64 / CH;

  float8 acc = {0.f, 0.f, 0.f, 0.f, 0.f, 0.f, 0.f, 0.f};
  if (j == 0)
    acc = __builtin_convertvector(*(const half8*)&G[(long)i * F + c * 8], float8);
  const int e0 = offs[i], e1 = offs[i + 1];
  for (int e = e0 + j; e < e1; e += JS) {
    const int s = esrc[e];
    acc += __builtin_convertvector(*(const half8*)&G[(long)s * F + c * 8], float8);
  }
#pragma unroll
  for (int off = CH; off < 64; off <<= 1)
#pragma unroll
    for (int k = 0; k < 8; ++k) acc[k] += __shfl_xor(acc[k], off);

  const float dv = dis[i];
  if constexpr (MODE == 2) {
    float p = 0.f;
#pragma unroll
    for (int k = 0; k < 8; ++k) {
      const int col = c * 8 + k;
      float v = acc[k] * dv + b[col];
      v = LRELU(v);
      p += v * Wout[col];
    }
#pragma unroll
    for (int off = 1; off < CH; off <<= 1) p += __shfl_xor(p, off);
    if (lane == 0) ((float*)out)[i] = p + bout[0];
  } else {
    if (j == 0) {
      half8 hv;
#pragma unroll
      for (int k = 0; k < 8; ++k) {
        float v = acc[k] * dv;
        if constexpr (MODE == 1) { v += b[c * 8 + k]; v = LRELU(v); }
        hv[k] = (_Float16)v;
      }
      *(half8*)&((_Float16*)out)[(long)i * F + c * 8] = hv;
    }
  }
}

// ---------------------------------------------------------------------------

extern "C" void kernel_launch(void* const* d_in, const int* in_sizes, int n_in,
                              void* d_out, int out_size, void* d_ws, size_t ws_size,
                              hipStream_t stream) {
  const float* x     = (const float*)d_in[0];
  const int* eidx    = (const int*)d_in[1];
  const float* W_in  = (const float*)d_in[2];
  const float* b_in  = (const float*)d_in[3];
  const float* W1    = (const float*)d_in[4];
  const float* b1    = (const float*)d_in[5];
  const float* W2    = (const float*)d_in[6];
  const float* b2    = (const float*)d_in[7];
  const float* W3    = (const float*)d_in[8];
  const float* b3    = (const float*)d_in[9];
  const float* W_out = (const float*)d_in[10];
  const float* b_out = (const float*)d_in[11];
  float* out = (float*)d_out;

  const int N = in_sizes[0] / 128;
  const int E = in_sizes[1] / 2;
  const int* src = eidx;
  const int* dst = eidx + E;
  const int nb = (N + 255) / 256;

  // bump allocator on d_ws, 256 B aligned
  size_t off = 0;
  char* base = (char*)d_ws;
  auto alloc = [&](size_t bytes) -> void* {
    void* p = base + off;
    off = (off + bytes + 255) & ~(size_t)255;
    return p;
  };
  int* cnt        = (int*)alloc((size_t)2 * N * sizeof(int));  // cnt + cur
  int* cur        = cnt + N;
  int* offs       = (int*)alloc((size_t)(N + 4) * sizeof(int));
  int* bsum       = (int*)alloc(256 * sizeof(int));
  int* esrc       = (int*)alloc((size_t)E * sizeof(int));
  float* dis      = (float*)alloc((size_t)N * sizeof(float));
  _Float16* wt_in = (_Float16*)alloc((size_t)128 * 128 * 2);
  _Float16* wt1   = (_Float16*)alloc((size_t)256 * 128 * 2);  // Wt1[256,128]
  _Float16* wt2   = (_Float16*)alloc((size_t)128 * 256 * 2);  // Wt2[128,256]
  _Float16* wt3   = (_Float16*)alloc((size_t)64 * 128 * 2);   // Wt3[64,128]
  _Float16* buf1  = (_Float16*)alloc((size_t)N * 128 * 2);
  _Float16* buf2  = (_Float16*)alloc((size_t)N * 128 * 2);
  _Float16* buf3  = (_Float16*)alloc((size_t)N * 256 * 2);

  hipMemsetAsync(cnt, 0, (size_t)2 * N * sizeof(int), stream);

  const int gE = (E + 255) / 256;
  const int gN = (N + 255) / 256;
  const int gRows = (N + 63) / 64;
  const int gAgg = (N + 3) / 4;

  // weight transpose+convert (independent of CSR)
  k_wt<<<dim3(1, 128), 256, 0, stream>>>(W_in, wt_in, 128, 128);
  k_wt<<<dim3(1, 128), 256, 0, stream>>>(W1, wt1, 128, 256);
  k_wt<<<dim3(1, 256), 256, 0, stream>>>(W2, wt2, 256, 128);
  k_wt<<<dim3(1, 128), 256, 0, stream>>>(W3, wt3, 128, 64);

  // CSR build
  k_count<<<gE, 256, 0, stream>>>(dst, cnt, E);
  k_dis<<<gN, 256, 0, stream>>>(cnt, dis, N);
  k_scan1<<<nb, 256, 0, stream>>>(cnt, offs, bsum, N);
  k_scan2<<<1, 256, 0, stream>>>(bsum, nb);
  k_scan3<<<nb, 256, 0, stream>>>(offs, bsum, N, E);
  k_fill<<<gE, 256, 0, stream>>>(src, dst, offs, cur, esrc, E);

  // g0 = dis .* lrelu(x @ W_in + b_in)
  k_gemm<128, 128, 0, float><<<gRows, 256, 0, stream>>>(x, wt_in, b_in, dis,
                                                        buf1, N);
  // a0 = A h0
  k_agg<128, 0><<<gAgg, 256, 0, stream>>>(buf1, esrc, offs, dis, nullptr,
                                          nullptr, nullptr, buf2, N);
  // h1 = lrelu(a0 @ W1 + b1)
  k_gemm<128, 256, 1, _Float16><<<gRows, 256, 0, stream>>>(buf2, wt1, b1,
                                                           nullptr, buf3, N);
  // g2 = dis .* (h1 @ W2)
  k_gemm<256, 128, 2, _Float16><<<gRows, 256, 0, stream>>>(buf3, wt2, nullptr,
                                                           dis, buf1, N);
  // h2 = lrelu(A-agg(g2) + b2)
  k_agg<128, 1><<<gAgg, 256, 0, stream>>>(buf1, esrc, offs, dis, b2,
                                          nullptr, nullptr, buf2, N);
  // g3 = dis .* (h2 @ W3)
  k_gemm<128, 64, 2, _Float16><<<gRows, 256, 0, stream>>>(buf2, wt3, nullptr,
                                                          dis, buf3, N);
  // out = lrelu(A-agg(g3) + b3) @ W_out + b_out
  k_agg<64, 2><<<gAgg, 256, 0, stream>>>(buf3, esrc, offs, dis, b3,
                                         W_out, b_out, out, N);
}